// Round 1
// baseline (331.844 us; speedup 1.0000x reference)
//
#include <hip/hip_runtime.h>
#include <stdint.h>

// xxh32 primes
#define XP2 2246822519u
#define XP3 3266489917u
#define XP4 668265263u
#define XP5 374761393u

constexpr int EMB_LEVELS = 1000000;
constexpr int F = 20;

__device__ __forceinline__ uint32_t rotl32(uint32_t v, int r) {
    return (v << r) | (v >> (32 - r));
}

// One 16-lane group per (n,f) pair: lane i copies float4 #i of the 64-float
// embedding row (16 lanes x 16B = 256B, fully coalesced on both sides).
__global__ __launch_bounds__(256) void ue_kernel(
    const int* __restrict__ x,
    const int* __restrict__ fnum,
    const float4* __restrict__ emb,   // [EMB_LEVELS * 16] float4 rows
    float4* __restrict__ out,         // [N * F * 16] float4
    int total_pairs)
{
    int t    = blockIdx.x * blockDim.x + threadIdx.x;
    int pair = t >> 4;          // (n*F + f)
    int lane = t & 15;
    if (pair >= total_pairs) return;

    int n = pair / F;
    int f = pair - n * F;

    uint32_t val  = (uint32_t)x[n];
    uint32_t seed = (uint32_t)fnum[f];

    // xxh32 of a single 4-byte little-endian word
    uint32_t acc = seed + XP5 + 4u;
    acc += val * XP3;
    acc = rotl32(acc, 17) * XP4;
    acc ^= acc >> 15;
    acc *= XP2;
    acc ^= acc >> 13;
    acc *= XP3;
    acc ^= acc >> 16;

    uint32_t idx = acc % (uint32_t)EMB_LEVELS;

    out[(size_t)pair * 16 + lane] = emb[(size_t)idx * 16 + lane];
}

extern "C" void kernel_launch(void* const* d_in, const int* in_sizes, int n_in,
                              void* d_out, int out_size, void* d_ws, size_t ws_size,
                              hipStream_t stream) {
    const int*   x    = (const int*)d_in[0];     // [N] int32
    const int*   fnum = (const int*)d_in[1];     // [F] int32
    const float* emb  = (const float*)d_in[2];   // [EMB_LEVELS, 64] f32
    float*       out  = (float*)d_out;           // [N, F*64] f32

    int n_rows = in_sizes[0];                    // N = 16384
    int total_pairs = n_rows * F;                // 327,680
    int total_threads = total_pairs * 16;        // 5,242,880
    int block = 256;
    int grid = (total_threads + block - 1) / block;

    ue_kernel<<<grid, block, 0, stream>>>(
        x, fnum, (const float4*)emb, (float4*)out, total_pairs);
}